// Round 2
// baseline (1203.537 us; speedup 1.0000x reference)
//
#include <hip/hip_runtime.h>

// CWTConv2D: x (32,512,512) f32 -> round; k (32,3,3) -> round+clip to {-1,0,1},
// spatially flipped conv (VALID) -> out (32,510,510,32) NHWC f32, +round(bias), relu.
//
// Layout: grid (4 j-tiles, 510 rows, 32 batch), block 256.
//   tid: f4 = tid&7 (filter quad), jq = tid>>3 (j-quad within 128-wide tile).
//   Each thread: 4 consecutive j x 4 filters = 16 outputs, x window loaded as
//   float4+float2 per row (3 rows) -> 6 vector loads per 16 outputs.

#define BATCH 32
#define H 512
#define W 512
#define NF 32
#define HO 510
#define WO 510

__global__ __launch_bounds__(256) void cwt_conv_kernel(
    const float* __restrict__ x,
    const float* __restrict__ kw,
    const float* __restrict__ bias,
    float* __restrict__ out)
{
    const int tid = threadIdx.x;
    const int f4  = tid & 7;    // filter quad: filters 4*f4 .. 4*f4+3
    const int jq  = tid >> 3;   // 0..31: j-quad within this block's 128-wide tile
    const int i   = blockIdx.y; // output row
    const int b   = blockIdx.z;
    const int j0  = blockIdx.x * 128 + jq * 4;   // max 508

    // Quantized, spatially-flipped weights. Tap t=(di*3+dj) uses kw[f][2-di][2-dj].
    float wq[9][4];
    float bq[4];
#pragma unroll
    for (int c = 0; c < 4; ++c) {
        int f = f4 * 4 + c;
#pragma unroll
        for (int t = 0; t < 9; ++t) {
            float v = rintf(kw[f * 9 + (8 - t)]);
            wq[t][c] = fminf(fmaxf(v, -1.0f), 1.0f);
        }
        bq[c] = rintf(bias[f]);
    }

    // Load + round the 3x6 x-window (rows i..i+2, cols j0..j0+5).
    const float* rp = x + ((size_t)(b * H + i) * W + j0);
    const bool have6 = (j0 <= W - 8);   // j0+5 <= 511; false only at j0==508
    float xr[3][6];
#pragma unroll
    for (int r = 0; r < 3; ++r) {
        const float4 v4 = *reinterpret_cast<const float4*>(rp + (size_t)r * W);
        xr[r][0] = rintf(v4.x);
        xr[r][1] = rintf(v4.y);
        xr[r][2] = rintf(v4.z);
        xr[r][3] = rintf(v4.w);
        if (have6) {
            const float2 v2 = *reinterpret_cast<const float2*>(rp + (size_t)r * W + 4);
            xr[r][4] = rintf(v2.x);
            xr[r][5] = rintf(v2.y);
        } else {
            xr[r][4] = 0.0f;   // feeds only outputs j>=510, which are masked
            xr[r][5] = 0.0f;
        }
    }

    float4* out4 = reinterpret_cast<float4*>(out);
    const int obase = ((b * HO + i) * WO + j0) * (NF / 4) + f4;  // float4 units

#pragma unroll
    for (int jj = 0; jj < 4; ++jj) {
        const int j = j0 + jj;
        float a0 = bq[0], a1 = bq[1], a2 = bq[2], a3 = bq[3];
#pragma unroll
        for (int r = 0; r < 3; ++r) {
#pragma unroll
            for (int dj = 0; dj < 3; ++dj) {
                const float xv = xr[r][jj + dj];
                const int t = r * 3 + dj;
                a0 = fmaf(xv, wq[t][0], a0);
                a1 = fmaf(xv, wq[t][1], a1);
                a2 = fmaf(xv, wq[t][2], a2);
                a3 = fmaf(xv, wq[t][3], a3);
            }
        }
        if (j < WO) {
            float4 o;
            o.x = fmaxf(a0, 0.0f);
            o.y = fmaxf(a1, 0.0f);
            o.z = fmaxf(a2, 0.0f);
            o.w = fmaxf(a3, 0.0f);
            out4[obase + jj * (NF / 4)] = o;
        }
    }
}

extern "C" void kernel_launch(void* const* d_in, const int* in_sizes, int n_in,
                              void* d_out, int out_size, void* d_ws, size_t ws_size,
                              hipStream_t stream) {
    const float* x    = (const float*)d_in[0];
    const float* kw   = (const float*)d_in[1];
    const float* bias = (const float*)d_in[2];
    float* out = (float*)d_out;

    dim3 grid(4, HO, BATCH);   // 4 x 510 x 32 = 65280 blocks
    dim3 block(256);
    cwt_conv_kernel<<<grid, block, 0, stream>>>(x, kw, bias, out);
}

// Round 4
// 1191.988 us; speedup vs baseline: 1.0097x; 1.0097x over previous
//
#include <hip/hip_runtime.h>

// CWTConv2D: x (32,512,512) f32 -> round; k (32,3,3) -> round+clip to {-1,0,1},
// spatially flipped conv (VALID) -> out (32,510,510,32) NHWC f32, +round(bias), relu.
//
// R3 = R2 intent with a compile fix: __builtin_nontemporal_store requires a
// native vector type, not HIP_vector_type. Use ext_vector_type(4) float.

#define BATCH 32
#define H 512
#define W 512
#define NF 32
#define HO 510
#define WO 510

typedef float vfloat4 __attribute__((ext_vector_type(4)));

__global__ __launch_bounds__(256) void cwt_conv_kernel(
    const float* __restrict__ x,
    const float* __restrict__ kw,
    const float* __restrict__ bias,
    float* __restrict__ out)
{
    const int tid = threadIdx.x;
    const int f4  = tid & 7;    // filter quad: filters 4*f4 .. 4*f4+3
    const int jq  = tid >> 3;   // 0..31: j-quad within this block's 128-wide tile
    const int i   = blockIdx.y; // output row
    const int b   = blockIdx.z;
    const int j0  = blockIdx.x * 128 + jq * 4;   // max 508

    // Quantized, spatially-flipped weights. Tap t=(di*3+dj) uses kw[f][2-di][2-dj].
    float wq[9][4];
    float bq[4];
#pragma unroll
    for (int c = 0; c < 4; ++c) {
        int f = f4 * 4 + c;
#pragma unroll
        for (int t = 0; t < 9; ++t) {
            float v = rintf(kw[f * 9 + (8 - t)]);
            wq[t][c] = fminf(fmaxf(v, -1.0f), 1.0f);
        }
        bq[c] = rintf(bias[f]);
    }

    // Load + round the 3x6 x-window (rows i..i+2, cols j0..j0+5).
    const float* rp = x + ((size_t)(b * H + i) * W + j0);
    const bool have6 = (j0 <= W - 8);   // j0+5 <= 511; false only at j0==508
    float xr[3][6];
#pragma unroll
    for (int r = 0; r < 3; ++r) {
        const float4 v4 = *reinterpret_cast<const float4*>(rp + (size_t)r * W);
        xr[r][0] = rintf(v4.x);
        xr[r][1] = rintf(v4.y);
        xr[r][2] = rintf(v4.z);
        xr[r][3] = rintf(v4.w);
        if (have6) {
            const float2 v2 = *reinterpret_cast<const float2*>(rp + (size_t)r * W + 4);
            xr[r][4] = rintf(v2.x);
            xr[r][5] = rintf(v2.y);
        } else {
            xr[r][4] = 0.0f;   // feeds only outputs j>=510, which are masked
            xr[r][5] = 0.0f;
        }
    }

    vfloat4* out4 = reinterpret_cast<vfloat4*>(out);
    const int obase = ((b * HO + i) * WO + j0) * (NF / 4) + f4;  // float4 units

#pragma unroll
    for (int jj = 0; jj < 4; ++jj) {
        const int j = j0 + jj;
        float a0 = bq[0], a1 = bq[1], a2 = bq[2], a3 = bq[3];
#pragma unroll
        for (int r = 0; r < 3; ++r) {
#pragma unroll
            for (int dj = 0; dj < 3; ++dj) {
                const float xv = xr[r][jj + dj];
                const int t = r * 3 + dj;
                a0 = fmaf(xv, wq[t][0], a0);
                a1 = fmaf(xv, wq[t][1], a1);
                a2 = fmaf(xv, wq[t][2], a2);
                a3 = fmaf(xv, wq[t][3], a3);
            }
        }
        if (j < WO) {
            vfloat4 o;
            o.x = fmaxf(a0, 0.0f);
            o.y = fmaxf(a1, 0.0f);
            o.z = fmaxf(a2, 0.0f);
            o.w = fmaxf(a3, 0.0f);
            __builtin_nontemporal_store(o, &out4[obase + jj * (NF / 4)]);
        }
    }
}

extern "C" void kernel_launch(void* const* d_in, const int* in_sizes, int n_in,
                              void* d_out, int out_size, void* d_ws, size_t ws_size,
                              hipStream_t stream) {
    const float* x    = (const float*)d_in[0];
    const float* kw   = (const float*)d_in[1];
    const float* bias = (const float*)d_in[2];
    float* out = (float*)d_out;

    dim3 grid(4, HO, BATCH);   // 4 x 510 x 32 = 65280 blocks
    dim3 block(256);
    cwt_conv_kernel<<<grid, block, 0, stream>>>(x, kw, bias, out);
}

// Round 5
// 1064.703 us; speedup vs baseline: 1.1304x; 1.1195x over previous
//
#include <hip/hip_runtime.h>

// CWTConv2D: x (32,512,512) f32 -> round; k (32,3,3) -> round+clip to {-1,0,1},
// spatially flipped conv (VALID) -> out (32,510,510,32) NHWC f32, +round(bias), relu.
//
// R4: 16-wide j-blocking. One block = one output row (b,i); thread = 4 filters
// x 16 consecutive j = 64 outputs. Weight-quantize setup amortized 4x vs R3.
// Stores remain nontemporal (1.065 GB pure stream).

#define BATCH 32
#define H 512
#define W 512
#define NF 32
#define HO 510
#define WO 510

typedef float vfloat4 __attribute__((ext_vector_type(4)));

__global__ __launch_bounds__(256) void cwt_conv_kernel(
    const float* __restrict__ x,
    const float* __restrict__ kw,
    const float* __restrict__ bias,
    float* __restrict__ out)
{
    const int tid = threadIdx.x;
    const int f4  = tid & 7;    // filter quad: filters 4*f4 .. 4*f4+3
    const int jq  = tid >> 3;   // 0..31: 16-wide j group
    const int i   = blockIdx.x; // output row 0..509
    const int b   = blockIdx.y;
    const int j0  = jq * 16;    // 0..496

    // Quantized, spatially-flipped weights. Tap t=(di*3+dj) uses kw[f][2-di][2-dj].
    float wq[9][4];
    float bq[4];
#pragma unroll
    for (int c = 0; c < 4; ++c) {
        int f = f4 * 4 + c;
#pragma unroll
        for (int t = 0; t < 9; ++t) {
            float v = rintf(kw[f * 9 + (8 - t)]);
            wq[t][c] = fminf(fmaxf(v, -1.0f), 1.0f);
        }
        bq[c] = rintf(bias[f]);
    }

    // Load + round the 3x18 x-window (rows i..i+2, cols j0..j0+17).
    const float* rp = x + ((size_t)(b * H + i) * W + j0);
    const bool tail = (jq != 31);   // jq==31: cols 512,513 OOB, feed only masked outputs
    float xr[3][18];
#pragma unroll
    for (int r = 0; r < 3; ++r) {
        const float* rr = rp + (size_t)r * W;
#pragma unroll
        for (int q = 0; q < 4; ++q) {
            const float4 v4 = *reinterpret_cast<const float4*>(rr + q * 4);
            xr[r][q * 4 + 0] = rintf(v4.x);
            xr[r][q * 4 + 1] = rintf(v4.y);
            xr[r][q * 4 + 2] = rintf(v4.z);
            xr[r][q * 4 + 3] = rintf(v4.w);
        }
        if (tail) {
            const float2 v2 = *reinterpret_cast<const float2*>(rr + 16);
            xr[r][16] = rintf(v2.x);
            xr[r][17] = rintf(v2.y);
        } else {
            xr[r][16] = 0.0f;
            xr[r][17] = 0.0f;
        }
    }

    vfloat4* out4 = reinterpret_cast<vfloat4*>(out);
    const int obase = ((b * HO + i) * WO + j0) * (NF / 4) + f4;  // float4 units

#pragma unroll
    for (int jj = 0; jj < 16; ++jj) {
        float a0 = bq[0], a1 = bq[1], a2 = bq[2], a3 = bq[3];
#pragma unroll
        for (int r = 0; r < 3; ++r) {
#pragma unroll
            for (int dj = 0; dj < 3; ++dj) {
                const float xv = xr[r][jj + dj];
                const int t = r * 3 + dj;
                a0 = fmaf(xv, wq[t][0], a0);
                a1 = fmaf(xv, wq[t][1], a1);
                a2 = fmaf(xv, wq[t][2], a2);
                a3 = fmaf(xv, wq[t][3], a3);
            }
        }
        if (j0 + jj < WO) {
            vfloat4 o;
            o.x = fmaxf(a0, 0.0f);
            o.y = fmaxf(a1, 0.0f);
            o.z = fmaxf(a2, 0.0f);
            o.w = fmaxf(a3, 0.0f);
            __builtin_nontemporal_store(o, &out4[obase + jj * (NF / 4)]);
        }
    }
}

extern "C" void kernel_launch(void* const* d_in, const int* in_sizes, int n_in,
                              void* d_out, int out_size, void* d_ws, size_t ws_size,
                              hipStream_t stream) {
    const float* x    = (const float*)d_in[0];
    const float* kw   = (const float*)d_in[1];
    const float* bias = (const float*)d_in[2];
    float* out = (float*)d_out;

    dim3 grid(HO, BATCH);   // 510 x 32 = 16320 blocks, one output row each
    dim3 block(256);
    cwt_conv_kernel<<<grid, block, 0, stream>>>(x, kw, bias, out);
}